// Round 3
// baseline (61.873 us; speedup 1.0000x reference)
//
#include <hip/hip_runtime.h>
#include <math.h>

// Problem constants
#define BB   16
#define HH   112
#define WW   112
#define CC   64
#define KK   8
#define EPSF 1e-6f
#define LN2F 0.69314718055994530942f

// 2D register tile per thread: HPT output rows x WPT output cols.
// Block = 256 threads = 64 channels x 4 w-groups -> tile 4h x 16w x 64c.
// Grid = B * (H/HPT) * (W/16) = 16*28*7 = 3136 blocks.
#define HPT  4
#define WPT  4
#define NROW (HPT + 8)    // 12 rows incl. +/-4 halo
#define NCOLS (WPT + 8)   // 12 cols incl. +/-4 halo

template<bool HE, bool WE>
__device__ __forceinline__ void do_tile(const float* __restrict__ x,
                                        float* __restrict__ out,
                                        int b, int h0, int w0, int c,
                                        float s1, float s2, float s3, float s4,
                                        const float* cen, const float* wid)
{
    // Row base pointers (wave-uniform -> SGPR base + lane voffset loads)
    const float* rowptr[NROW];
    float rvalid[NROW];
#pragma unroll
    for (int L = 0; L < NROW; ++L) {
        const int hr = h0 + L - 4;
        const int hc = HE ? min(max(hr, 0), HH - 1) : hr;
        rowptr[L] = x + (size_t)(b * HH + hc) * WW * CC;
        rvalid[L] = HE ? (((unsigned)hr < (unsigned)HH) ? 1.0f : 0.0f) : 1.0f;
    }

    float mu1[HPT][WPT], mu2[HPT][WPT], mu3[HPT][WPT], mu4[HPT][WPT];
#pragma unroll
    for (int hi = 0; hi < HPT; ++hi)
#pragma unroll
        for (int wi = 0; wi < WPT; ++wi) {
            mu1[hi][wi] = 0.f; mu2[hi][wi] = 0.f;
            mu3[hi][wi] = 0.f; mu4[hi][wi] = 0.f;
        }

    // 3 chunks of 4 columns: load 48 values (deep clause), then consume.
#pragma unroll
    for (int ch = 0; ch < 3; ++ch) {
        int off[4];
#pragma unroll
        for (int j = 0; j < 4; ++j) {
            const int wc = w0 - 4 + ch * 4 + j;
            const int wcc = WE ? min(max(wc, 0), WW - 1) : wc;
            off[j] = wcc * CC + c;      // interior: off[0] + j*CC -> imm folds
        }
        float a[4][NROW];
#pragma unroll
        for (int L = 0; L < NROW; ++L)
#pragma unroll
            for (int j = 0; j < 4; ++j)
                a[j][L] = rowptr[L][off[j]];

#pragma unroll
        for (int j = 0; j < 4; ++j) {
            const int i = ch * 4 + j;    // local column index 0..11
            // vertical inclusive prefix over the 12 rows
            float p[NROW];
            float run = 0.0f;
#pragma unroll
            for (int L = 0; L < NROW; ++L) {
                float v = fabsf(a[j][L]);
                if (HE) v *= rvalid[L];
                run += v;
                p[L] = run;
            }
            float cmask = 1.0f;
            if (WE) cmask = ((unsigned)(w0 - 4 + i) < (unsigned)WW) ? 1.0f : 0.0f;

#pragma unroll
            for (int hi = 0; hi < HPT; ++hi) {
                // window rows (local): [hi+4-r, hi+4+r] -> p[hi+4+r]-p[hi+3-r]
                float v1 = p[hi + 5] - p[hi + 2];
                float v2 = p[hi + 6] - p[hi + 1];
                float v3 = p[hi + 7] - p[hi + 0];
                float v4 = (hi >= 1) ? (p[hi + 8] - p[hi - 1]) : p[8];
                if (WE) { v1 *= cmask; v2 *= cmask; v3 *= cmask; v4 *= cmask; }
#pragma unroll
                for (int wi = 0; wi < WPT; ++wi) {
                    const int ci = wi + 4;   // output col in local coords
                    if (i >= ci - 1 && i <= ci + 1) mu1[hi][wi] += v1;
                    if (i >= ci - 2 && i <= ci + 2) mu2[hi][wi] += v2;
                    if (i >= ci - 3 && i <= ci + 3) mu3[hi][wi] += v3;
                    if (i >= ci - 4 && i <= ci + 4) mu4[hi][wi] += v4;
                }
            }
        }
    }

    // center x values (L1-hot reload), batched
    float xv[HPT][WPT];
#pragma unroll
    for (int hi = 0; hi < HPT; ++hi)
#pragma unroll
        for (int wi = 0; wi < WPT; ++wi)
            xv[hi][wi] = rowptr[hi + 4][(w0 + wi) * CC + c];

#pragma unroll
    for (int hi = 0; hi < HPT; ++hi) {
        int rows1 = 3, rows2 = 5, rows3 = 7, rows4 = 9;
        if (HE) {
            const int g = h0 + hi;
            rows1 = min(g + 1, HH - 1) - max(g - 1, 0) + 1;
            rows2 = min(g + 2, HH - 1) - max(g - 2, 0) + 1;
            rows3 = min(g + 3, HH - 1) - max(g - 3, 0) + 1;
            rows4 = min(g + 4, HH - 1) - max(g - 4, 0) + 1;
        }
        float* orow = out + (size_t)(b * HH + h0 + hi) * WW * CC;
#pragma unroll
        for (int wi = 0; wi < WPT; ++wi) {
            float e1, e2, e3, e4;
            if (WE) {
                const int w = w0 + wi;
                const int cols1 = min(w + 1, WW - 1) - max(w - 1, 0) + 1;
                const int cols2 = min(w + 2, WW - 1) - max(w - 2, 0) + 1;
                const int cols3 = min(w + 3, WW - 1) - max(w - 3, 0) + 1;
                const int cols4 = min(w + 4, WW - 1) - max(w - 4, 0) + 1;
                e1 = (float)(rows1 * cols1) * EPSF;
                e2 = (float)(rows2 * cols2) * EPSF;
                e3 = (float)(rows3 * cols3) * EPSF;
                e4 = (float)(rows4 * cols4) * EPSF;
            } else {
                e1 = (float)(rows1 * 3) * EPSF;
                e2 = (float)(rows2 * 5) * EPSF;
                e3 = (float)(rows3 * 7) * EPSF;
                e4 = (float)(rows4 * 9) * EPSF;
            }

            const float alpha = s1 * __log2f(mu1[hi][wi] + e1) +
                                s2 * __log2f(mu2[hi][wi] + e2) +
                                s3 * __log2f(mu3[hi][wi] + e3) +
                                s4 * __log2f(mu4[hi][wi] + e4);

            float sc = 0.0f;
#pragma unroll
            for (int k = 0; k < KK; ++k) {
                const float d = alpha - cen[k];
                sc += fmaxf(__fmaf_rn(-wid[k], d * d, 1.0f), 0.0f);
            }

            const float sig = __fdividef(1.0f, 1.0f + __expf(-sc));
            orow[(w0 + wi) * CC + c] = xv[hi][wi] + sig;
        }
    }
}

__global__ __launch_bounds__(256, 3)
void l2hist_singularity_kernel(const float* __restrict__ x,
                               const float* __restrict__ sw,
                               const float* __restrict__ centers,
                               const float* __restrict__ widths,
                               float* __restrict__ out)
{
    const int tid = threadIdx.x;
    const int c   = tid & 63;        // lanes contiguous in channel -> coalesced
    const int wq  = tid >> 6;        // wave index: 4-wide w sub-tile

    int t = blockIdx.x;
    const int wt = t % 7;  t /= 7;   // W/16 = 7 tiles
    const int ht = t % 28;           // H/4  = 28 tiles
    const int b  = t / 28;
    const int h0 = ht * HPT;
    const int w0 = wt * 16 + wq * WPT;

    const float s1 = sw[0] * LN2F, s2 = sw[1] * LN2F;
    const float s3 = sw[2] * LN2F, s4 = sw[3] * LN2F;

    float cen[KK], wid[KK];
#pragma unroll
    for (int k = 0; k < KK; ++k) {
        cen[k] = centers[c * KK + k];
        wid[k] = widths[c * KK + k];
    }

    const bool he = (h0 < 4) | (h0 + HPT - 1 + 4 >= HH);   // block-uniform
    const bool we = (w0 < 4) | (w0 + WPT - 1 + 4 >= WW);   // wave-uniform

    if (!he) {
        if (!we) do_tile<false, false>(x, out, b, h0, w0, c, s1, s2, s3, s4, cen, wid);
        else     do_tile<false, true >(x, out, b, h0, w0, c, s1, s2, s3, s4, cen, wid);
    } else {
        if (!we) do_tile<true,  false>(x, out, b, h0, w0, c, s1, s2, s3, s4, cen, wid);
        else     do_tile<true,  true >(x, out, b, h0, w0, c, s1, s2, s3, s4, cen, wid);
    }
}

extern "C" void kernel_launch(void* const* d_in, const int* in_sizes, int n_in,
                              void* d_out, int out_size, void* d_ws, size_t ws_size,
                              hipStream_t stream) {
    const float* x       = (const float*)d_in[0];
    const float* sw      = (const float*)d_in[1];
    const float* centers = (const float*)d_in[2];
    const float* widths  = (const float*)d_in[3];
    float* out           = (float*)d_out;

    const int blocks = BB * (HH / HPT) * (WW / 16);   // 3136
    l2hist_singularity_kernel<<<blocks, 256, 0, stream>>>(x, sw, centers, widths, out);
}